// Round 10
// baseline (88.807 us; speedup 1.0000x reference)
//
#include <hip/hip_runtime.h>
#include <math.h>

#define NFRAMES 64
#define NATOMS  512
#define NSEG    129795     // sum_{i=0}^{508} (509-i) = 509*510/2
#define NROWS   509        // row i: j in [i+2, 510], len = 509-i
#define NBLK    255        // block b: rows {b, 508-b} (510 pairs; b=254: 255)
#define BLOCK   256        // thread: 2 consecutive pairs x 2 frames (v2 lanes)
#define RUN     2

typedef float v2 __attribute__((ext_vector_type(2)));

__device__ __forceinline__ v2 v2s(float x) { v2 r; r.x = x; r.y = x; return r; }
__device__ __forceinline__ v2 v2mk(float a, float b) { v2 r; r.x = a; r.y = b; return r; }
__device__ __forceinline__ v2 vfma(v2 a, v2 b, v2 c) { return __builtin_elementwise_fma(a, b, c); }
__device__ __forceinline__ v2 vabs(v2 x) { v2 r; r.x = fabsf(x.x); r.y = fabsf(x.y); return r; }
__device__ __forceinline__ v2 vmin1(v2 a) { v2 r; r.x = fminf(a.x, 1.0f); r.y = fminf(a.y, 1.0f); return r; }
__device__ __forceinline__ v2 vsqrt_raw(v2 x) {
    v2 r; r.x = __builtin_amdgcn_sqrtf(x.x); r.y = __builtin_amdgcn_sqrtf(x.y); return r;
}
__device__ __forceinline__ v2 vrsq_raw(v2 x) {
    v2 r; r.x = __builtin_amdgcn_rsqf(x.x); r.y = __builtin_amdgcn_rsqf(x.y); return r;
}
__device__ __forceinline__ v2 vcopysign(v2 m, v2 s) {
    v2 r; r.x = copysignf(m.x, s.x); r.y = copysignf(m.y, s.y); return r;
}

// 2-coeff minimax on (pi/2 - asin x)/sqrt(1-x): |err| <= 0.0058 rad/asin;
// <= 0.0037 on wr worst-case vs 2e-2 threshold (validated R8: absmax 0.0039).
__device__ __forceinline__ v2 vasin(v2 x) {
    v2 ax = vmin1(vabs(x));                       // folds jnp.clip
    v2 p  = vfma(ax, v2s(-0.156582f), v2s(1.565019f));
    v2 r  = v2s(1.57079632679f) - vsqrt_raw(v2s(1.0f) - ax) * p;
    return vcopysign(r, x);
}

struct v23 { v2 x, y, z; };

__device__ __forceinline__ v23 vcross(v23 a, v23 b) {
    return v23{ vfma(a.y, b.z, -(a.z * b.y)),
                vfma(a.z, b.x, -(a.x * b.z)),
                vfma(a.x, b.y, -(a.y * b.x)) };
}
__device__ __forceinline__ v2 vdot(v23 a, v23 b) {
    return vfma(a.x, b.x, vfma(a.y, b.y, a.z * b.z));
}

// LDS: atom a -> v2-slot 3a + a/4 (x,y,z pairs over 2 staged frames;
// 8B pad per 4 atoms -> <=2-way bank conflicts = free).
__device__ __forceinline__ int b2(int a) { return 3 * a + (a >> 2); }
#define LDS_V2 1680        // b2(514)+2 = 1672 used

__global__ __launch_bounds__(BLOCK, 6) void writhe_kernel(
    const float* __restrict__ xyz,      // (NFRAMES, NATOMS, 3)
    float*       __restrict__ out)      // (NFRAMES, NSEG)
{
    __shared__ v2 sp[LDS_V2];           // 13.4 KB

    const int b  = blockIdx.x;          // 0..254
    const int f0 = blockIdx.y * 2;      // frames f0, f0+1 in v2 lanes
    const float* fxa = xyz + (size_t)f0 * (NATOMS * 3);
    const float* fxb = fxa + NATOMS * 3;
    for (int a = threadIdx.x; a < NATOMS; a += BLOCK) {
        const float* g0 = fxa + 3 * a;
        const float* g1 = fxb + 3 * a;
        const int s = b2(a);
        sp[s + 0] = v2mk(g0[0], g1[0]);
        sp[s + 1] = v2mk(g0[1], g1[1]);
        sp[s + 2] = v2mk(g0[2], g1[2]);
    }
    if (threadIdx.x < 3) {              // zero-pad atoms 512..514
        const int s = b2(NATOMS + threadIdx.x);
        sp[s + 0] = v2s(0.f); sp[s + 1] = v2s(0.f); sp[s + 2] = v2s(0.f);
    }
    __syncthreads();

    // R5-proven zero-waste partition: rows {b, 508-b}, na+nb <= 256 exact.
    const int rowA = b;
    const int rowB = 508 - b;
    const int lenA = NROWS - rowA;                       // 509 - b
    const int lenB = (rowB == rowA) ? 0 : NROWS - rowB;  // b + 1 (0 at middle)
    const int na   = (lenA + 1) >> 1;

    const int t    = threadIdx.x;
    const bool inA = (t < na);
    const int row  = inA ? rowA : rowB;
    const int len  = inA ? lenA : lenB;
    const int k0   = (inA ? t : (t - na)) << 1;          // first pair in row
    if (k0 >= len) return;

    const int j0 = row + 2 + k0;        // pairs k0,k0+1 use atoms j0..j0+2

    // Packed (frame0,frame1) loads: 3 atoms + P1 + P2, 15 ds_read_b64.
    v2 Ax[RUN + 1], Ay[RUN + 1], Az[RUN + 1];
    #pragma unroll
    for (int m = 0; m <= RUN; ++m) {
        const int s = b2(j0 + m);
        Ax[m] = sp[s]; Ay[m] = sp[s + 1]; Az[m] = sp[s + 2];
    }
    const int sP1 = b2(row), sP2 = b2(row + 1);
    const v2 P1x = sp[sP1], P1y = sp[sP1 + 1], P1z = sp[sP1 + 2];
    const v2 P2x = sp[sP2], P2y = sp[sP2 + 1], P2z = sp[sP2 + 2];
    const v23 s12{P2x - P1x, P2y - P1y, P2z - P1z};      // r12

    // Seed chain: h = -c4(k0) = u0 x v0 (c4 = r23 x r13 = v x u).
    v23 u0{Ax[0] - P1x, Ay[0] - P1y, Az[0] - P1z};
    v23 vv0{Ax[0] - P2x, Ay[0] - P2y, Az[0] - P2z};
    v23 h  = vcross(u0, vv0);
    v2 in4 = vrsq_raw(vdot(h, h));

    const int off = NROWS * row - (row * (row - 1)) / 2;
    const size_t base0 = (size_t)f0 * NSEG + off + k0;
    const int rem = len - k0;           // 1 or 2

    #pragma unroll
    for (int k = 0; k < RUN; ++k) {
        // On-the-fly subs (exact CSE of the reference's own subtractions).
        v23 uk {Ax[k]     - P1x, Ay[k]     - P1y, Az[k]     - P1z};  // r13
        v23 uk1{Ax[k + 1] - P1x, Ay[k + 1] - P1y, Az[k + 1] - P1z};  // r14
        v23 vk {Ax[k]     - P2x, Ay[k]     - P2y, Az[k]     - P2z};  // r23
        v23 vk1{Ax[k + 1] - P2x, Ay[k + 1] - P2y, Az[k + 1] - P2z};  // r24
        v23 w34{Ax[k + 1] - Ax[k], Ay[k + 1] - Ay[k], Az[k + 1] - Az[k]};

        v23 c1 = vcross(uk,  uk1);      // r13 x r14
        v23 c2 = vcross(uk1, vk1);      // r14 x r24
        v23 c3 = vcross(vk1, vk);       // r24 x r23

        v2 in1 = vrsq_raw(vdot(c1, c1));
        v2 in2 = vrsq_raw(vdot(c2, c2));
        v2 in3 = vrsq_raw(vdot(c3, c3));

        v2 d12 = vdot(c1, c2) * (in1 * in2);
        v2 d23 = vdot(c2, c3) * (in2 * in3);
        v2 e34 = vdot(c3, h)  * (in3 * in4);     // = -d34
        v2 e41 = vdot(h, c1)  * (in4 * in1);     // = -d41

        v2 theta = (vasin(d12) + vasin(d23)) - (vasin(e34) + vasin(e41));

        v2 sv = vdot(vcross(w34, s12), uk);      // exact reference sign expr
        v2 wr = theta * vcopysign(v2s(0.15915494309189535f), sv);
        wr.x = (sv.x == 0.0f) ? 0.0f : wr.x;
        wr.y = (sv.y == 0.0f) ? 0.0f : wr.y;

        if (k < rem) {
            out[base0 + k]        = wr.x;        // frame f0
            out[base0 + k + NSEG] = wr.y;        // frame f0+1
        }
        h = c2; in4 = in2;                       // c4(k+1) = -c2(k)
    }
}

extern "C" void kernel_launch(void* const* d_in, const int* in_sizes, int n_in,
                              void* d_out, int out_size, void* d_ws, size_t ws_size,
                              hipStream_t stream) {
    const float* xyz = (const float*)d_in[0];
    float*       out = (float*)d_out;   // segs (d_in[1]) unused: indices analytic

    dim3 grid(NBLK, NFRAMES / 2);
    writhe_kernel<<<grid, BLOCK, 0, stream>>>(xyz, out);
}

// Round 11
// 83.324 us; speedup vs baseline: 1.0658x; 1.0658x over previous
//
#include <hip/hip_runtime.h>
#include <math.h>

#define NFRAMES 64
#define NATOMS  512
#define NSEG    129795     // sum_{i=0}^{508} (509-i) = 509*510/2
#define NROWS   509        // row i: j in [i+2, 510], len = 509-i
#define BLOCK   256        // two 128-thread halves, each one row-pair (R8 partition)
#define RUN     4          // consecutive pairs per thread (chained)

typedef float v2 __attribute__((ext_vector_type(2)));

__device__ __forceinline__ v2 v2s(float x) { v2 r; r.x = x; r.y = x; return r; }
__device__ __forceinline__ v2 v2mk(float a, float b) { v2 r; r.x = a; r.y = b; return r; }
__device__ __forceinline__ v2 vfma(v2 a, v2 b, v2 c) { return __builtin_elementwise_fma(a, b, c); }
__device__ __forceinline__ v2 vabs(v2 x) { v2 r; r.x = fabsf(x.x); r.y = fabsf(x.y); return r; }
__device__ __forceinline__ v2 vmin1(v2 a) { v2 r; r.x = fminf(a.x, 1.0f); r.y = fminf(a.y, 1.0f); return r; }
__device__ __forceinline__ v2 vsqrt_raw(v2 x) {
    v2 r; r.x = __builtin_amdgcn_sqrtf(x.x); r.y = __builtin_amdgcn_sqrtf(x.y); return r;
}
__device__ __forceinline__ v2 vrsq_raw(v2 x) {
    v2 r; r.x = __builtin_amdgcn_rsqf(x.x); r.y = __builtin_amdgcn_rsqf(x.y); return r;
}
__device__ __forceinline__ v2 vcopysign(v2 m, v2 s) {
    v2 r; r.x = copysignf(m.x, s.x); r.y = copysignf(m.y, s.y); return r;
}

// 2-coeff minimax on (pi/2 - asin x)/sqrt(1-x): |err| <= 0.0058 rad/asin;
// <= 0.0037 on wr worst-case vs 2e-2 threshold (validated R8: absmax 0.0039).
__device__ __forceinline__ v2 vasin(v2 x) {
    v2 ax = vmin1(vabs(x));                       // folds jnp.clip
    v2 p  = vfma(ax, v2s(-0.156582f), v2s(1.565019f));
    v2 r  = v2s(1.57079632679f) - vsqrt_raw(v2s(1.0f) - ax) * p;
    return vcopysign(r, x);
}

struct v23 { v2 x, y, z; };

__device__ __forceinline__ v23 vcross(v23 a, v23 b) {
    return v23{ vfma(a.y, b.z, -(a.z * b.y)),
                vfma(a.z, b.x, -(a.x * b.z)),
                vfma(a.x, b.y, -(a.y * b.x)) };
}
__device__ __forceinline__ v2 vdot(v23 a, v23 b) {
    return vfma(a.x, b.x, vfma(a.y, b.y, a.z * b.z));
}

// LDS: atom a -> v2-slot 3a + a/4 (x,y,z pairs over 2 staged frames;
// 8B pad per 4 atoms -> <=2-way bank conflicts = free).
__device__ __forceinline__ int b2(int a) { return 3 * a + (a >> 2); }
#define LDS_V2 1680        // b2(514)+2 = 1672 used

__global__ __launch_bounds__(BLOCK) void writhe_kernel(
    const float* __restrict__ xyz,      // (NFRAMES, NATOMS, 3)
    float*       __restrict__ out)      // (NFRAMES, NSEG)
{
    __shared__ v2 sp[LDS_V2];           // 13.4 KB, shared by both halves

    const int f0 = blockIdx.y * 2;      // frames f0, f0+1 in v2 lanes
    const float* fxa = xyz + (size_t)f0 * (NATOMS * 3);
    const float* fxb = fxa + NATOMS * 3;
    for (int a = threadIdx.x; a < NATOMS; a += BLOCK) {   // 2 atoms/thread
        const float* g0 = fxa + 3 * a;
        const float* g1 = fxb + 3 * a;
        const int s = b2(a);
        sp[s + 0] = v2mk(g0[0], g1[0]);
        sp[s + 1] = v2mk(g0[1], g1[1]);
        sp[s + 2] = v2mk(g0[2], g1[2]);
    }
    if (threadIdx.x < 3) {              // zero-pad atoms 512..514 (tail runs)
        const int s = b2(NATOMS + threadIdx.x);
        sp[s + 0] = v2s(0.f); sp[s + 1] = v2s(0.f); sp[s + 2] = v2s(0.f);
    }
    __syncthreads();

    // Each 128-thread half handles one row-pair q (R8-validated partition):
    // q 0..252 -> rows {q+2, 508-q}; 253 -> row 1; 254 -> row 0; 255 -> row 255.
    const int q  = blockIdx.x * 2 + (threadIdx.x >> 7);   // 0..255
    const int t  = threadIdx.x & 127;

    int rowA, rowB, lenB;
    if (q < 253)       { rowA = q + 2; rowB = 508 - q; lenB = q + 1; }
    else if (q == 253) { rowA = 1;     rowB = 0;       lenB = 0;     }
    else if (q == 254) { rowA = 0;     rowB = 0;       lenB = 0;     }
    else               { rowA = 255;   rowB = 0;       lenB = 0;     }
    const int lenA = NROWS - rowA;
    const int na   = (lenA + 3) >> 2;

    const bool inA = (t < na);
    const int row  = inA ? rowA : rowB;
    const int len  = inA ? lenA : lenB;
    const int k0   = (inA ? t : (t - na)) << 2;
    if (k0 >= len) return;

    const int j0 = row + 2 + k0;        // pairs k0..k0+3 use atoms j0..j0+4

    // Packed (frame0,frame1) loads: 5 atoms + P1,P2 (identical to R8).
    v2 Ax[RUN + 1], Ay[RUN + 1], Az[RUN + 1];
    #pragma unroll
    for (int m = 0; m <= RUN; ++m) {
        const int s = b2(j0 + m);
        Ax[m] = sp[s]; Ay[m] = sp[s + 1]; Az[m] = sp[s + 2];
    }
    const int sP1 = b2(row), sP2 = b2(row + 1);
    const v2 P1x = sp[sP1], P1y = sp[sP1 + 1], P1z = sp[sP1 + 2];
    const v2 P2x = sp[sP2], P2y = sp[sP2 + 1], P2z = sp[sP2 + 2];

    // Exact-CSE subs (same subtractions the reference performs):
    v23 u[RUN + 1], vv[RUN + 1], w34[RUN];
    #pragma unroll
    for (int m = 0; m <= RUN; ++m) {
        u[m]  = v23{Ax[m] - P1x, Ay[m] - P1y, Az[m] - P1z};   // r13/r14 pool
        vv[m] = v23{Ax[m] - P2x, Ay[m] - P2y, Az[m] - P2z};   // r23/r24 pool
    }
    #pragma unroll
    for (int m = 0; m < RUN; ++m)
        w34[m] = v23{Ax[m+1] - Ax[m], Ay[m+1] - Ay[m], Az[m+1] - Az[m]}; // r34
    const v23 s12{P2x - P1x, P2y - P1y, P2z - P1z};           // r12

    // h = -c4: seed h(0) = u0 x v0; chain h(k) = c2(k-1) since
    // c4(k) = v_k x u_k = -(u_k x v_k) = -c2(k-1). Reuse |h|^2, rsq.
    v23 h  = vcross(u[0], vv[0]);
    v2 in4 = vrsq_raw(vdot(h, h));

    // 32-bit output indexing: max index 64*129795 ~ 8.3M < 2^31.
    const int off   = NROWS * row - (row * (row - 1)) / 2;
    const int base0 = f0 * NSEG + off + k0;
    const int rem   = len - k0;         // 1..4

    #pragma unroll
    for (int k = 0; k < RUN; ++k) {
        v23 c1 = vcross(u[k],      u[k + 1]);    // r13 x r14
        v23 c2 = vcross(u[k + 1],  vv[k + 1]);   // r14 x r24
        v23 c3 = vcross(vv[k + 1], vv[k]);       // r24 x r23

        v2 in1 = vrsq_raw(vdot(c1, c1));
        v2 in2 = vrsq_raw(vdot(c2, c2));
        v2 in3 = vrsq_raw(vdot(c3, c3));

        v2 d12 = vdot(c1, c2) * (in1 * in2);
        v2 d23 = vdot(c2, c3) * (in2 * in3);
        v2 e34 = vdot(c3, h)  * (in3 * in4);     // = -d34
        v2 e41 = vdot(h, c1)  * (in4 * in1);     // = -d41

        v2 theta = (vasin(d12) + vasin(d23)) - (vasin(e34) + vasin(e41));

        // sign: exact reference expression (r34 x r12) . r13 — do NOT
        // substitute det shortcuts (true discontinuity at coplanar crossings;
        // an ulp-level sign flip vs ref costs absmax ~ 2|wr|).
        v2 sv = vdot(vcross(w34[k], s12), u[k]);
        v2 wr = theta * vcopysign(v2s(0.15915494309189535f), sv);
        wr.x = (sv.x == 0.0f) ? 0.0f : wr.x;
        wr.y = (sv.y == 0.0f) ? 0.0f : wr.y;

        if (k < rem) {
            out[base0 + k]        = wr.x;        // frame f0
            out[base0 + k + NSEG] = wr.y;        // frame f0+1
        }
        h = c2; in4 = in2;                       // c4(k+1) = -c2(k)
    }
}

extern "C" void kernel_launch(void* const* d_in, const int* in_sizes, int n_in,
                              void* d_out, int out_size, void* d_ws, size_t ws_size,
                              hipStream_t stream) {
    const float* xyz = (const float*)d_in[0];
    float*       out = (float*)d_out;   // segs (d_in[1]) unused: indices analytic

    dim3 grid(128, NFRAMES / 2);        // x: 2 row-pairs/block; y: 2 frames/block
    writhe_kernel<<<grid, BLOCK, 0, stream>>>(xyz, out);
}